// Round 12
// baseline (159.307 us; speedup 1.0000x reference)
//
#include <hip/hip_runtime.h>
#include <hip/hip_bf16.h>

typedef _Float16 f16;
typedef __attribute__((ext_vector_type(4))) float f32x4;
typedef __attribute__((ext_vector_type(8))) _Float16 f16x8;
typedef __attribute__((ext_vector_type(4))) _Float16 f16x4;
typedef __attribute__((ext_vector_type(2))) __fp16 hf2;

#define Bv 2
#define Nv 2048
#define DIMv 1024
#define Hv 16
#define DHv 64
#define INNERv 1024
#define QKV3v 3072

__device__ __forceinline__ void gload16(const void* g, void* l) {
  __builtin_amdgcn_global_load_lds(
      (const __attribute__((address_space(1))) void*)g,
      (__attribute__((address_space(3))) void*)l, 16, 0, 0);
}

// ---------------- LayerNorm: fp32 in -> f16 out ----------------
__global__ __launch_bounds__(256) void ln_kernel(
    const float* __restrict__ x, const float* __restrict__ g,
    const float* __restrict__ bb, f16* __restrict__ h) {
  const int row = blockIdx.x;
  const int t = threadIdx.x;
  const float4 v = reinterpret_cast<const float4*>(x + (size_t)row * DIMv)[t];
  float s = v.x + v.y + v.z + v.w;
  float sq = v.x * v.x + v.y * v.y + v.z * v.z + v.w * v.w;
#pragma unroll
  for (int o = 32; o > 0; o >>= 1) {
    s += __shfl_down(s, o);
    sq += __shfl_down(sq, o);
  }
  __shared__ float red[8];
  __shared__ float musr[2];
  const int wave = t >> 6, lane = t & 63;
  if (lane == 0) { red[wave] = s; red[4 + wave] = sq; }
  __syncthreads();
  if (t == 0) {
    const float S = red[0] + red[1] + red[2] + red[3];
    const float SQ = red[4] + red[5] + red[6] + red[7];
    const float mu = S * (1.0f / DIMv);
    const float var = SQ * (1.0f / DIMv) - mu * mu;
    musr[0] = mu;
    musr[1] = rsqrtf(var + 1e-5f);
  }
  __syncthreads();
  const float mu = musr[0], rs = musr[1];
  const float4 gv = reinterpret_cast<const float4*>(g)[t];
  const float4 bv = reinterpret_cast<const float4*>(bb)[t];
  f16x4 o;
  o.x = (f16)((v.x - mu) * rs * gv.x + bv.x);
  o.y = (f16)((v.y - mu) * rs * gv.y + bv.y);
  o.z = (f16)((v.z - mu) * rs * gv.z + bv.z);
  o.w = (f16)((v.w - mu) * rs * gv.w + bv.w);
  *reinterpret_cast<f16x4*>(&h[(size_t)row * DIMv + t * 4]) = o;
}

// ------------- Precompute cos/sin of rotary freqs -----------
__global__ __launch_bounds__(256) void rotcs_kernel(
    const float* __restrict__ rot, float* __restrict__ c,
    float* __restrict__ s, int n) {
  const int i = blockIdx.x * blockDim.x + threadIdx.x;
  if (i < n) {
    const float f = rot[i];
    c[i] = cosf(f);
    s[i] = sinf(f);
  }
}

// ------------- Transpose + convert: W[K][N] fp32 -> Wt[N][K] f16 -----------
__global__ __launch_bounds__(256) void transpose_f16(
    const float* __restrict__ W, f16* __restrict__ Wt, int K, int N) {
  __shared__ float tile[64][65];
  const int t = threadIdx.x;
  const int n0 = blockIdx.x * 64, k0 = blockIdx.y * 64;
#pragma unroll
  for (int i = 0; i < 16; ++i) {
    const int idx = t + i * 256;
    const int r = idx >> 6, c = idx & 63;
    tile[r][c] = W[(size_t)(k0 + r) * N + n0 + c];
  }
  __syncthreads();
#pragma unroll
  for (int i = 0; i < 16; ++i) {
    const int idx = t + i * 256;
    const int r = idx >> 6, c = idx & 63;
    Wt[(size_t)(n0 + r) * K + k0 + c] = (f16)tile[c][r];
  }
}

// ---- 256x256-tile f16 MFMA GEMM, BK=32, 4-deep pipelined (QKV GEMM) ----
// 8 waves (2M x 4N), per-wave 128x64 output. Stage K-tile kt+3 at P1 of kt
// (buffer freed 2 barriers earlier); counted vmcnt(8) at P0; XOR swizzle
// chunk^=(row>>1)&3 on both sides (pre-swizzled global src + swz ds_read).
template <int EPI>
__global__ __launch_bounds__(512, 2) void gemm_mfma256(
    const f16* __restrict__ A, const f16* __restrict__ Bt,
    const float* __restrict__ bias, void* __restrict__ Cout,
    const float* __restrict__ cs, const float* __restrict__ sn,
    int M, int N, int K) {
  __shared__ __align__(16) f16 AsbF[4 * 8192];  // 4 bufs x [256][32]
  __shared__ __align__(16) f16 BsbF[4 * 8192];
  const int t = threadIdx.x;
  const int l = t & 63, w = t >> 6;
  const int wm = w >> 2, wn = w & 3;
  const int row0 = blockIdx.y * 256, col0 = blockIdx.x * 256;
  const int rl = l & 15, kg = l >> 4;

  // staging slots: i0 = t, i1 = t+512; row = i>>2, gchunk = (i&3)^((row>>1)&3)
  const int i0 = t, i1 = t + 512;
  const int rA0 = i0 >> 2, cח0 = (i0 & 3) ^ ((rA0 >> 1) & 3);
  const int rA1 = i1 >> 2, cח1 = (i1 & 3) ^ ((rA1 >> 1) & 3);
  const f16* gA0 = &A[(size_t)(row0 + rA0) * K + cח0 * 8];
  const f16* gA1 = &A[(size_t)(row0 + rA1) * K + cח1 * 8];
  const f16* gB0 = &Bt[(size_t)(col0 + rA0) * K + cח0 * 8];
  const f16* gB1 = &Bt[(size_t)(col0 + rA1) * K + cח1 * 8];

  const f32x4 zero = {0.f, 0.f, 0.f, 0.f};
  f32x4 acc[8][4];
#pragma unroll
  for (int m = 0; m < 8; ++m)
#pragma unroll
    for (int n = 0; n < 4; ++n) acc[m][n] = zero;

#define STAGE256(bufi, kk)                                  \
  {                                                         \
    gload16(gA0 + (kk) * 32, &AsbF[(bufi)*8192 + i0 * 8]);  \
    gload16(gA1 + (kk) * 32, &AsbF[(bufi)*8192 + i1 * 8]);  \
    gload16(gB0 + (kk) * 32, &BsbF[(bufi)*8192 + i0 * 8]);  \
    gload16(gB1 + (kk) * 32, &BsbF[(bufi)*8192 + i1 * 8]);  \
  }

  const int nkt = K >> 5;
  STAGE256(0, 0);
  STAGE256(1, 1);
  STAGE256(2, 2);

  for (int kt = 0; kt < nkt; ++kt) {
    const int buf = kt & 3;
    const f16* Ab = &AsbF[buf * 8192];
    const f16* Bb = &BsbF[buf * 8192];

    // ---------------- P0 ----------------
    if (kt + 2 < nkt)
      asm volatile("s_waitcnt vmcnt(8)" ::: "memory");
    else if (kt + 1 < nkt)
      asm volatile("s_waitcnt vmcnt(4)" ::: "memory");
    else
      asm volatile("s_waitcnt vmcnt(0)" ::: "memory");
    __builtin_amdgcn_s_barrier();
    __builtin_amdgcn_sched_barrier(0);

    f16x8 bfr[4], afr[4];
#pragma unroll
    for (int n = 0; n < 4; ++n) {
      const int rowB = wn * 64 + n * 16 + rl;
      bfr[n] = *reinterpret_cast<const f16x8*>(
          &Bb[rowB * 32 + ((kg ^ ((rowB >> 1) & 3)) << 3)]);
    }
#pragma unroll
    for (int m = 0; m < 4; ++m) {
      const int rowA = wm * 128 + m * 16 + rl;
      afr[m] = *reinterpret_cast<const f16x8*>(
          &Ab[rowA * 32 + ((kg ^ ((rowA >> 1) & 3)) << 3)]);
    }
    __builtin_amdgcn_s_setprio(1);
#pragma unroll
    for (int m = 0; m < 4; ++m)
#pragma unroll
      for (int n = 0; n < 4; ++n)
        acc[m][n] =
            __builtin_amdgcn_mfma_f32_16x16x32_f16(afr[m], bfr[n], acc[m][n], 0, 0, 0);
    __builtin_amdgcn_s_setprio(0);

    // ---------------- P1 ----------------
    asm volatile("" ::: "memory");
    __builtin_amdgcn_s_barrier();
    __builtin_amdgcn_sched_barrier(0);
    if (kt + 3 < nkt) STAGE256((kt + 3) & 3, kt + 3);
#pragma unroll
    for (int m = 0; m < 4; ++m) {
      const int rowA = wm * 128 + (m + 4) * 16 + rl;
      afr[m] = *reinterpret_cast<const f16x8*>(
          &Ab[rowA * 32 + ((kg ^ ((rowA >> 1) & 3)) << 3)]);
    }
    __builtin_amdgcn_s_setprio(1);
#pragma unroll
    for (int m = 0; m < 4; ++m)
#pragma unroll
      for (int n = 0; n < 4; ++n)
        acc[m + 4][n] =
            __builtin_amdgcn_mfma_f32_16x16x32_f16(afr[m], bfr[n], acc[m + 4][n], 0, 0, 0);
    __builtin_amdgcn_s_setprio(0);
    asm volatile("" ::: "memory");
  }
#undef STAGE256

  // ---------------- epilogue ----------------
#pragma unroll
  for (int m = 0; m < 8; ++m) {
#pragma unroll
    for (int n = 0; n < 4; ++n) {
#pragma unroll
      for (int jr = 0; jr < 4; ++jr) {
        const int rg = row0 + wm * 128 + m * 16 + kg * 4 + jr;
        const int cg = col0 + wn * 64 + n * 16 + rl;
        const float v = acc[m][n][jr] + bias[cg];
        if (EPI == 0) {
          ((float*)Cout)[(size_t)rg * N + cg] = v;
        } else {
          const float p = __shfl_xor(v, 1);
          const size_t cb = (size_t)rg * DHv + (cg & 63);
          const float cc = cs[cb], ss = sn[cb];
          // forward rotary: even d: v*c - p*s ; odd d: v*c + p*s
          const float y = (l & 1) ? (v * cc + p * ss) : (v * cc - p * ss);
          ((f16*)Cout)[(size_t)rg * N + cg] = (f16)y;
        }
      }
    }
  }
}

// ------- f16 MFMA GEMM, 128x128 tile, BK=32, counted-vmcnt pipeline -------
// (used for the output projection; grid there is 256 blocks = 1/CU)
template <int EPI>
__global__ __launch_bounds__(256) void gemm_mfma(
    const f16* __restrict__ A, const f16* __restrict__ Bt,
    const float* __restrict__ bias, void* __restrict__ Cout,
    const float* __restrict__ cs, const float* __restrict__ sn,
    int M, int N, int K) {
  __shared__ __align__(16) f16 Asb[2][128 * 32];
  __shared__ __align__(16) f16 Bsb[2][128 * 32];
  const int t = threadIdx.x;
  const int l = t & 63, w = t >> 6;
  const int wr = w >> 1, wc = w & 1;
  const int row0 = blockIdx.y * 128, col0 = blockIdx.x * 128;

  const int i1 = t, i2 = t + 256;
  const f16* ga1 = &A[(size_t)(row0 + (i1 >> 2)) * K + (i1 & 3) * 8];
  const f16* ga2 = &A[(size_t)(row0 + (i2 >> 2)) * K + (i2 & 3) * 8];
  const f16* gb1 = &Bt[(size_t)(col0 + (i1 >> 2)) * K + (i1 & 3) * 8];
  const f16* gb2 = &Bt[(size_t)(col0 + (i2 >> 2)) * K + (i2 & 3) * 8];
  const int a_off1 = w * 512, a_off2 = w * 512 + 2048;

  const int rl = l & 15, kg = l >> 4;
  const int ar = (wr * 64 + rl) * 32 + kg * 8;
  const int br = (wc * 64 + rl) * 32 + kg * 8;

  const f32x4 zero = {0.f, 0.f, 0.f, 0.f};
  f32x4 acc[4][4];
#pragma unroll
  for (int m = 0; m < 4; ++m)
#pragma unroll
    for (int n = 0; n < 4; ++n) acc[m][n] = zero;

#define GSTAGE(buf, kk)                           \
  {                                               \
    gload16(ga1 + (kk)*32, &Asb[buf][a_off1]);    \
    gload16(ga2 + (kk)*32, &Asb[buf][a_off2]);    \
    gload16(gb1 + (kk)*32, &Bsb[buf][a_off1]);    \
    gload16(gb2 + (kk)*32, &Bsb[buf][a_off2]);    \
  }

  const int nt = K >> 5;
  GSTAGE(0, 0);

  for (int kt = 0; kt < nt; ++kt) {
    const int cur = kt & 1;
    if (kt + 1 < nt) {
      GSTAGE(cur ^ 1, kt + 1);
      asm volatile("s_waitcnt vmcnt(4)" ::: "memory");
    } else {
      asm volatile("s_waitcnt vmcnt(0)" ::: "memory");
    }
    __builtin_amdgcn_s_barrier();
    __builtin_amdgcn_sched_barrier(0);
    f16x8 af[4], bf[4];
#pragma unroll
    for (int m = 0; m < 4; ++m)
      af[m] = *reinterpret_cast<const f16x8*>(&Asb[cur][ar + m * 16 * 32]);
#pragma unroll
    for (int n = 0; n < 4; ++n)
      bf[n] = *reinterpret_cast<const f16x8*>(&Bsb[cur][br + n * 16 * 32]);
#pragma unroll
    for (int m = 0; m < 4; ++m)
#pragma unroll
      for (int n = 0; n < 4; ++n)
        acc[m][n] =
            __builtin_amdgcn_mfma_f32_16x16x32_f16(af[m], bf[n], acc[m][n], 0, 0, 0);
    asm volatile("" ::: "memory");
    __builtin_amdgcn_s_barrier();
    __builtin_amdgcn_sched_barrier(0);
  }
#undef GSTAGE

#pragma unroll
  for (int m = 0; m < 4; ++m) {
#pragma unroll
    for (int n = 0; n < 4; ++n) {
#pragma unroll
      for (int jr = 0; jr < 4; ++jr) {
        const int rg = row0 + wr * 64 + m * 16 + kg * 4 + jr;
        const int cg = col0 + wc * 64 + n * 16 + rl;
        const float v = acc[m][n][jr] + bias[cg];
        if (EPI == 0) {
          ((float*)Cout)[(size_t)rg * N + cg] = v;
        } else {
          const float p = __shfl_xor(v, 1);
          const size_t cb = (size_t)rg * DHv + (cg & 63);
          const float cc = cs[cb], ss = sn[cb];
          const float y = (l & 1) ? (v * cc + p * ss) : (v * cc - p * ss);
          ((f16*)Cout)[(size_t)rg * N + cg] = (f16)y;
        }
      }
    }
  }
}

// ---- V transpose: qkvf V-slab [n][d] -> vT[(b,h,d)][n'] with key perm ----
__global__ __launch_bounds__(256) void transpose_v(
    const f16* __restrict__ qkvf, f16* __restrict__ vT) {
  const int nt = blockIdx.x, hh = blockIdx.y, b = blockIdx.z;
  const int t = threadIdx.x;
  __shared__ __align__(16) f16 tile[64][80];  // [n-local][d]
  const int nl = t >> 3, dc = (t & 7) * 8;
#pragma unroll
  for (int half = 0; half < 2; ++half) {
    const int n = nl + half * 32;
    *reinterpret_cast<f16x8*>(&tile[n][dc]) = *reinterpret_cast<const f16x8*>(
        &qkvf[(size_t)(b * Nv + nt * 64 + n) * QKV3v + 2 * INNERv + hh * DHv + dc]);
  }
  __syncthreads();
  const int c0 = (t & 7) * 8;
  const int kwp = c0 >> 5, kgp = (c0 >> 3) & 3;
#pragma unroll
  for (int half = 0; half < 2; ++half) {
    const int d = (t >> 3) + half * 32;
    union { f16 e[8]; f16x8 v; } uo;
#pragma unroll
    for (int j = 0; j < 8; ++j) {
      const int mk = (j >> 2) & 1, jr = j & 3;
      const int kap = kwp * 32 + mk * 16 + kgp * 4 + jr;
      uo.e[j] = tile[kap][d];
    }
    *reinterpret_cast<f16x8*>(
        &vT[((size_t)((b * Hv + hh) * DHv + d)) * Nv + nt * 64 + c0]) = uo.v;
  }
}

// --------- MFMA flash attention v5: swapped QK^T, register P, O^T ---------
__global__ __launch_bounds__(256, 4) void attn_mfma(
    const f16* __restrict__ qkvf, const f16* __restrict__ vT,
    const float* __restrict__ cs, const float* __restrict__ sn,
    f16* __restrict__ ao) {
  const int wg = blockIdx.x;
  const int swz = (wg & 7) * 128 + (wg >> 3);
  const int qb = swz & 31;
  const int hh = (swz >> 5) & 15;
  const int b = swz >> 9;
  const int t = threadIdx.x, l = t & 63, w = t >> 6;
  const int qw = w >> 1, kw = w & 1;
  const int rl = l & 15, kg = l >> 4;

  __shared__ __align__(16) f16 KsB[2][64 * 64];
  __shared__ __align__(16) f16 VtB[2][64 * 64];
  __shared__ float Lbuf[2][2][32];

  const size_t qrow0 = (size_t)(b * Nv + qb * 64 + qw * 32);
  f16x8 bq[2][2];
#pragma unroll
  for (int nq = 0; nq < 2; ++nq)
#pragma unroll
    for (int ks = 0; ks < 2; ++ks)
      bq[nq][ks] = *reinterpret_cast<const f16x8*>(
          &qkvf[(qrow0 + nq * 16 + rl) * QKV3v + hh * DHv + ks * 32 + kg * 8]);

  const f32x4 zero = {0.f, 0.f, 0.f, 0.f};
  f32x4 o_acc[2][4];
  float l_part[2] = {0.f, 0.f};
#pragma unroll
  for (int nq = 0; nq < 2; ++nq)
#pragma unroll
    for (int m2 = 0; m2 < 4; ++m2) o_acc[nq][m2] = zero;

  const int srow = t >> 3, sc0 = (t & 7) * 8;
  const f16* vtbh = vT + (size_t)((b * Hv + hh) * DHv) * Nv;
  f16x8 kr0, kr1, vr0, vr1;

#define LOADKV(tile)                                                           \
  {                                                                            \
    const size_t kb0 =                                                         \
        (size_t)(b * Nv + (tile)*64 + srow) * QKV3v + INNERv + hh * DHv + sc0; \
    kr0 = *reinterpret_cast<const f16x8*>(&qkvf[kb0]);                         \
    kr1 = *reinterpret_cast<const f16x8*>(&qkvf[kb0 + (size_t)32 * QKV3v]);    \
    const size_t vb0 = (size_t)srow * Nv + (tile)*64 + sc0;                    \
    vr0 = *reinterpret_cast<const f16x8*>(&vtbh[vb0]);                         \
    vr1 = *reinterpret_cast<const f16x8*>(&vtbh[vb0 + (size_t)32 * Nv]);       \
  }
#define STOREKV(buf)                                                           \
  {                                                                            \
    const int r1 = srow + 32;                                                  \
    *reinterpret_cast<f16x8*>(                                                 \
        &KsB[buf][(srow << 6) | (sc0 ^ ((srow & 7) << 3))]) = kr0;             \
    *reinterpret_cast<f16x8*>(                                                 \
        &KsB[buf][(r1 << 6) | (sc0 ^ ((r1 & 7) << 3))]) = kr1;                 \
    *reinterpret_cast<f16x8*>(                                                 \
        &VtB[buf][(srow << 6) | (sc0 ^ ((srow & 7) << 3))]) = vr0;             \
    *reinterpret_cast<f16x8*>(                                                 \
        &VtB[buf][(r1 << 6) | (sc0 ^ ((r1 & 7) << 3))]) = vr1;                 \
  }

  LOADKV(0);
  STOREKV(0);
  LOADKV(1);
  __syncthreads();

  const float SC2 = 0.125f * 1.44269504f;

  for (int kt = 0; kt < 32; ++kt) {
    const int cur = kt & 1;
    const f16* Kc = &KsB[cur][0];
    const f16* Vc = &VtB[cur][0];

    f16x8 ak[2][2];
#pragma unroll
    for (int mk = 0; mk < 2; ++mk)
#pragma unroll
      for (int ks = 0; ks < 2; ++ks)
        ak[mk][ks] = *reinterpret_cast<const f16x8*>(
            &Kc[((kw * 32 + mk * 16 + rl) << 6) |
                ((ks * 32 + kg * 8) ^ ((rl & 7) << 3))]);
    f16x8 av[4];
#pragma unroll
    for (int m2 = 0; m2 < 4; ++m2)
      av[m2] = *reinterpret_cast<const f16x8*>(
          &Vc[((m2 * 16 + rl) << 6) |
              ((kw * 32 + kg * 8) ^ ((rl & 7) << 3))]);

    f32x4 sa[2][2];
#pragma unroll
    for (int mk = 0; mk < 2; ++mk)
#pragma unroll
      for (int nq = 0; nq < 2; ++nq) sa[mk][nq] = zero;
    __builtin_amdgcn_s_setprio(1);
#pragma unroll
    for (int ks = 0; ks < 2; ++ks)
#pragma unroll
      for (int mk = 0; mk < 2; ++mk)
#pragma unroll
        for (int nq = 0; nq < 2; ++nq)
          sa[mk][nq] = __builtin_amdgcn_mfma_f32_16x16x32_f16(
              ak[mk][ks], bq[nq][ks], sa[mk][nq], 0, 0, 0);
    __builtin_amdgcn_s_setprio(0);

    f16x8 pb[2];
#pragma unroll
    for (int nq = 0; nq < 2; ++nq) {
      float p00 = exp2f(fminf(sa[0][nq][0] * SC2, 13.0f));
      float p01 = exp2f(fminf(sa[0][nq][1] * SC2, 13.0f));
      float p02 = exp2f(fminf(sa[0][nq][2] * SC2, 13.0f));
      float p03 = exp2f(fminf(sa[0][nq][3] * SC2, 13.0f));
      float p10 = exp2f(fminf(sa[1][nq][0] * SC2, 13.0f));
      float p11 = exp2f(fminf(sa[1][nq][1] * SC2, 13.0f));
      float p12 = exp2f(fminf(sa[1][nq][2] * SC2, 13.0f));
      float p13 = exp2f(fminf(sa[1][nq][3] * SC2, 13.0f));
      l_part[nq] += ((p00 + p01) + (p02 + p03)) + ((p10 + p11) + (p12 + p13));
      union { hf2 h2[4]; f16x8 v; } u;
      u.h2[0] = __builtin_amdgcn_cvt_pkrtz(p00, p01);
      u.h2[1] = __builtin_amdgcn_cvt_pkrtz(p02, p03);
      u.h2[2] = __builtin_amdgcn_cvt_pkrtz(p10, p11);
      u.h2[3] = __builtin_amdgcn_cvt_pkrtz(p12, p13);
      pb[nq] = u.v;
    }

    __builtin_amdgcn_s_setprio(1);
#pragma unroll
    for (int nq = 0; nq < 2; ++nq)
#pragma unroll
      for (int m2 = 0; m2 < 4; ++m2)
        o_acc[nq][m2] = __builtin_amdgcn_mfma_f32_16x16x32_f16(
            av[m2], pb[nq], o_acc[nq][m2], 0, 0, 0);
    __builtin_amdgcn_s_setprio(0);

    if (kt < 31) STOREKV(1 - cur);
    if (kt < 30) LOADKV(kt + 2);
    __syncthreads();
  }

#pragma unroll
  for (int nq = 0; nq < 2; ++nq) {
    l_part[nq] += __shfl_xor(l_part[nq], 16);
    l_part[nq] += __shfl_xor(l_part[nq], 32);
  }
  if (kg == 0) {
    Lbuf[qw][kw][rl] = l_part[0];
    Lbuf[qw][kw][16 + rl] = l_part[1];
  }
  {
    char* ob = (qw == 0 ? (char*)KsB : (char*)VtB) + kw * 8192;
#pragma unroll
    for (int nq = 0; nq < 2; ++nq)
#pragma unroll
      for (int m2 = 0; m2 < 4; ++m2)
        *reinterpret_cast<f32x4*>(
            ob + (nq * 16 + rl) * 256 +
            ((m2 * 64 + kg * 16) ^ ((rl & 7) << 4))) = o_acc[nq][m2];
  }
  __syncthreads();
  {
    const int q_local = w * 16 + (l >> 2);
    const int qw_r = q_local >> 5, q_in = q_local & 31;
    const int d0 = (l & 3) * 16;
    char* rb = (qw_r == 0 ? (char*)KsB : (char*)VtB);
    const float linv = 1.0f / (Lbuf[qw_r][0][q_in] + Lbuf[qw_r][1][q_in]);
    const size_t nq_g = (size_t)(b * Nv + qb * 64 + q_local);
    const size_t cb = nq_g * DHv + d0;
    union { f16 e[16]; f16x8 v[2]; } uo;
#pragma unroll
    for (int j = 0; j < 4; ++j) {
      const unsigned off = q_in * 256 + (((l & 3) * 64 + j * 16) ^ ((q_in & 7) << 4));
      const f32x4 a = *reinterpret_cast<const f32x4*>(rb + off);
      const f32x4 c2 = *reinterpret_cast<const f32x4*>(rb + 8192 + off);
      const float4 csv = *reinterpret_cast<const float4*>(&cs[cb + j * 4]);
      const float4 snv = *reinterpret_cast<const float4*>(&sn[cb + j * 4]);
      const float o0 = (a[0] + c2[0]) * linv;
      const float o1 = (a[1] + c2[1]) * linv;
      const float o2 = (a[2] + c2[2]) * linv;
      const float o3 = (a[3] + c2[3]) * linv;
      uo.e[j * 4 + 0] = (f16)(o0 * csv.x + o1 * snv.x);
      uo.e[j * 4 + 1] = (f16)(o1 * csv.y - o0 * snv.y);
      uo.e[j * 4 + 2] = (f16)(o2 * csv.z + o3 * snv.z);
      uo.e[j * 4 + 3] = (f16)(o3 * csv.w - o2 * snv.w);
    }
    f16* aop = &ao[nq_g * INNERv + hh * DHv + d0];
    *reinterpret_cast<f16x8*>(aop) = uo.v[0];
    *reinterpret_cast<f16x8*>(aop + 8) = uo.v[1];
  }
#undef LOADKV
#undef STOREKV
}

extern "C" void kernel_launch(void* const* d_in, const int* in_sizes, int n_in,
                              void* d_out, int out_size, void* d_ws, size_t ws_size,
                              hipStream_t stream) {
  (void)in_sizes; (void)n_in; (void)out_size; (void)ws_size;
  const float* x = (const float*)d_in[0];
  const float* rot = (const float*)d_in[1];
  const float* ln_g = (const float*)d_in[2];
  const float* ln_b = (const float*)d_in[3];
  const float* w_qkv = (const float*)d_in[4];
  const float* b_qkv = (const float*)d_in[5];
  const float* w_out = (const float*)d_in[6];
  const float* b_out = (const float*)d_in[7];

  char* p = (char*)d_ws;
  f16* h = (f16*)p;            p += (size_t)Bv * Nv * DIMv * 2;
  float* cs = (float*)p;       p += (size_t)Bv * Nv * DHv * 4;
  float* sn = (float*)p;       p += (size_t)Bv * Nv * DHv * 4;
  f16* wqT = (f16*)p;          p += (size_t)QKV3v * DIMv * 2;
  f16* woT = (f16*)p;          p += (size_t)DIMv * INNERv * 2;
  f16* qkvf = (f16*)p;         p += (size_t)Bv * Nv * QKV3v * 2;
  f16* ao = (f16*)p;           p += (size_t)Bv * Nv * INNERv * 2;
  f16* vT = (f16*)p;           p += (size_t)Bv * Hv * DHv * Nv * 2;

  ln_kernel<<<dim3(Bv * Nv), dim3(256), 0, stream>>>(x, ln_g, ln_b, h);
  rotcs_kernel<<<dim3((Bv * Nv * DHv) / 256), dim3(256), 0, stream>>>(
      rot, cs, sn, Bv * Nv * DHv);
  transpose_f16<<<dim3(QKV3v / 64, DIMv / 64), dim3(256), 0, stream>>>(
      w_qkv, wqT, DIMv, QKV3v);
  transpose_f16<<<dim3(INNERv / 64, DIMv / 64), dim3(256), 0, stream>>>(
      w_out, woT, DIMv, INNERv);
  gemm_mfma256<1><<<dim3(QKV3v / 256, (Bv * Nv) / 256), dim3(512), 0, stream>>>(
      h, wqT, b_qkv, (void*)qkvf, cs, sn, Bv * Nv, QKV3v, DIMv);
  transpose_v<<<dim3(Nv / 64, Hv, Bv), dim3(256), 0, stream>>>(qkvf, vT);
  attn_mfma<<<dim3(1024), dim3(256), 0, stream>>>(qkvf, vT, cs, sn, ao);
  gemm_mfma<0><<<dim3(DIMv / 128, (Bv * Nv) / 128), dim3(256), 0, stream>>>(
      ao, woT, b_out, d_out, nullptr, nullptr, Bv * Nv, DIMv, INNERv);
}

// Round 13
// 151.831 us; speedup vs baseline: 1.0492x; 1.0492x over previous
//
#include <hip/hip_runtime.h>
#include <hip/hip_bf16.h>

typedef _Float16 f16;
typedef __attribute__((ext_vector_type(4))) float f32x4;
typedef __attribute__((ext_vector_type(8))) _Float16 f16x8;
typedef __attribute__((ext_vector_type(4))) _Float16 f16x4;
typedef __attribute__((ext_vector_type(2))) __fp16 hf2;

#define Bv 2
#define Nv 2048
#define DIMv 1024
#define Hv 16
#define DHv 64
#define INNERv 1024
#define QKV3v 3072

__device__ __forceinline__ void gload16(const void* g, void* l) {
  __builtin_amdgcn_global_load_lds(
      (const __attribute__((address_space(1))) void*)g,
      (__attribute__((address_space(3))) void*)l, 16, 0, 0);
}

// ---------------- LayerNorm: fp32 in -> f16 out ----------------
__global__ __launch_bounds__(256) void ln_kernel(
    const float* __restrict__ x, const float* __restrict__ g,
    const float* __restrict__ bb, f16* __restrict__ h) {
  const int row = blockIdx.x;
  const int t = threadIdx.x;
  const float4 v = reinterpret_cast<const float4*>(x + (size_t)row * DIMv)[t];
  float s = v.x + v.y + v.z + v.w;
  float sq = v.x * v.x + v.y * v.y + v.z * v.z + v.w * v.w;
#pragma unroll
  for (int o = 32; o > 0; o >>= 1) {
    s += __shfl_down(s, o);
    sq += __shfl_down(sq, o);
  }
  __shared__ float red[8];
  __shared__ float musr[2];
  const int wave = t >> 6, lane = t & 63;
  if (lane == 0) { red[wave] = s; red[4 + wave] = sq; }
  __syncthreads();
  if (t == 0) {
    const float S = red[0] + red[1] + red[2] + red[3];
    const float SQ = red[4] + red[5] + red[6] + red[7];
    const float mu = S * (1.0f / DIMv);
    const float var = SQ * (1.0f / DIMv) - mu * mu;
    musr[0] = mu;
    musr[1] = rsqrtf(var + 1e-5f);
  }
  __syncthreads();
  const float mu = musr[0], rs = musr[1];
  const float4 gv = reinterpret_cast<const float4*>(g)[t];
  const float4 bv = reinterpret_cast<const float4*>(bb)[t];
  f16x4 o;
  o.x = (f16)((v.x - mu) * rs * gv.x + bv.x);
  o.y = (f16)((v.y - mu) * rs * gv.y + bv.y);
  o.z = (f16)((v.z - mu) * rs * gv.z + bv.z);
  o.w = (f16)((v.w - mu) * rs * gv.w + bv.w);
  *reinterpret_cast<f16x4*>(&h[(size_t)row * DIMv + t * 4]) = o;
}

// ------------- Precompute cos/sin of rotary freqs -----------
__global__ __launch_bounds__(256) void rotcs_kernel(
    const float* __restrict__ rot, float* __restrict__ c,
    float* __restrict__ s, int n) {
  const int i = blockIdx.x * blockDim.x + threadIdx.x;
  if (i < n) {
    const float f = rot[i];
    c[i] = cosf(f);
    s[i] = sinf(f);
  }
}

// ------------- Transpose + convert: W[K][N] fp32 -> Wt[N][K] f16 -----------
__global__ __launch_bounds__(256) void transpose_f16(
    const float* __restrict__ W, f16* __restrict__ Wt, int K, int N) {
  __shared__ float tile[64][65];
  const int t = threadIdx.x;
  const int n0 = blockIdx.x * 64, k0 = blockIdx.y * 64;
#pragma unroll
  for (int i = 0; i < 16; ++i) {
    const int idx = t + i * 256;
    const int r = idx >> 6, c = idx & 63;
    tile[r][c] = W[(size_t)(k0 + r) * N + n0 + c];
  }
  __syncthreads();
#pragma unroll
  for (int i = 0; i < 16; ++i) {
    const int idx = t + i * 256;
    const int r = idx >> 6, c = idx & 63;
    Wt[(size_t)(n0 + r) * K + k0 + c] = (f16)tile[c][r];
  }
}

// ---- 256x256-tile f16 MFMA GEMM, BK=64, fine 4-phase pipeline (QKV) ----
// Per phase: {issue 1 half-tile gload -> vmcnt(6) -> barrier -> ds_reads ->
// lgkmcnt(0) -> 16 MFMA}. Half-tiles = k-halves; staged with lead 3-4 phases;
// vmcnt never 0 in steady state. LDS [2buf][2kh][256][32] per matrix, bank
// swizzle chunk^=(r&3)^((r>>2)&3) on global source + read (rule #21).
template <int EPI>
__global__ __launch_bounds__(512, 1) void gemm_mfma256(
    const f16* __restrict__ A, const f16* __restrict__ Bt,
    const float* __restrict__ bias, void* __restrict__ Cout,
    const float* __restrict__ cs, const float* __restrict__ sn,
    int M, int N, int K) {
  __shared__ __align__(16) f16 Abuf[32768];  // [buf2][kh2][256 r][32 k]
  __shared__ __align__(16) f16 Bbuf[32768];
  const int t = threadIdx.x, l = t & 63, w = t >> 6;
  const int wm = w >> 2, wn = w & 3;
  const int row0 = blockIdx.y * 256, col0 = blockIdx.x * 256;
  const int rl = l & 15, kg = l >> 4;

  // staging: wave w instr j covers local rows w*32+j*16..+16; lane l ->
  // row_local += l>>2, phys chunk l&3 holds global chunk (l&3)^sw(row)
  const int r0l = w * 32 + (l >> 2);
  const int r1l = r0l + 16;
  const int c0e = (((l & 3) ^ ((r0l & 3) ^ ((r0l >> 2) & 3))) << 3);
  const int c1e = (((l & 3) ^ ((r1l & 3) ^ ((r1l >> 2) & 3))) << 3);
  const f16* gA0 = &A[(size_t)(row0 + r0l) * K + c0e];
  const f16* gA1 = &A[(size_t)(row0 + r1l) * K + c1e];
  const f16* gB0 = &Bt[(size_t)(col0 + r0l) * K + c0e];
  const f16* gB1 = &Bt[(size_t)(col0 + r1l) * K + c1e];
  const int ldsw = w * 1024;  // wave's staging slot within a half (elements)

  const f32x4 zero = {0.f, 0.f, 0.f, 0.f};
  f32x4 acc[8][4];
#pragma unroll
  for (int m = 0; m < 8; ++m)
#pragma unroll
    for (int n = 0; n < 4; ++n) acc[m][n] = zero;

#define STA(kh, tile)                                                      \
  {                                                                        \
    const int db = (((tile)&1) << 14) + ((kh) << 13) + ldsw;               \
    gload16(gA0 + (size_t)(tile)*64 + (kh)*32, &Abuf[db]);                 \
    gload16(gA1 + (size_t)(tile)*64 + (kh)*32, &Abuf[db + 512]);           \
  }
#define STB(kh, tile)                                                      \
  {                                                                        \
    const int db = (((tile)&1) << 14) + ((kh) << 13) + ldsw;               \
    gload16(gB0 + (size_t)(tile)*64 + (kh)*32, &Bbuf[db]);                 \
    gload16(gB1 + (size_t)(tile)*64 + (kh)*32, &Bbuf[db + 512]);           \
  }
#define RDA(frag, mg, ks, cur)                                             \
  {                                                                        \
    const int r = wm * 128 + (mg)*16 + rl;                                 \
    frag = *reinterpret_cast<const f16x8*>(                                \
        &Abuf[((cur) << 14) + ((ks) << 13) + r * 32 +                      \
              ((kg ^ ((r & 3) ^ ((r >> 2) & 3))) << 3)]);                  \
  }
#define RDB(frag, n, ks, cur)                                              \
  {                                                                        \
    const int r = wn * 64 + (n)*16 + rl;                                   \
    frag = *reinterpret_cast<const f16x8*>(                                \
        &Bbuf[((cur) << 14) + ((ks) << 13) + r * 32 +                      \
              ((kg ^ ((r & 3) ^ ((r >> 2) & 3))) << 3)]);                  \
  }
#define MFMA_CLUSTER(mbase, afr, bfr)                                      \
  {                                                                        \
    asm volatile("s_waitcnt lgkmcnt(0)" ::: "memory");                     \
    __builtin_amdgcn_sched_barrier(0);                                     \
    __builtin_amdgcn_s_setprio(1);                                         \
    _Pragma("unroll") for (int m = 0; m < 4; ++m)                          \
        _Pragma("unroll") for (int n = 0; n < 4; ++n) acc[(mbase) + m][n] =\
        __builtin_amdgcn_mfma_f32_16x16x32_f16(afr[m], bfr[n],             \
                                               acc[(mbase) + m][n], 0, 0, 0);\
    __builtin_amdgcn_s_setprio(0);                                         \
  }

  const int nkt = K >> 6;  // BK=64
  // prologue: stage tile 0 fully, drain once
  STA(0, 0); STB(0, 0); STA(1, 0); STB(1, 0);
  asm volatile("s_waitcnt vmcnt(0)" ::: "memory");
  __builtin_amdgcn_s_barrier();

  f16x8 af[4], bf[4];
  for (int kt = 0; kt < nkt; ++kt) {
    const int cur = kt & 1;
    const bool pf = (kt + 1 < nkt);
    // ---- phase 0: ks=0, m-half 0 ----
    if (pf) {
      STA(0, kt + 1);
      asm volatile("s_waitcnt vmcnt(6)" ::: "memory");
    } else {
      asm volatile("s_waitcnt vmcnt(4)" ::: "memory");
    }
    __builtin_amdgcn_s_barrier();
    __builtin_amdgcn_sched_barrier(0);
#pragma unroll
    for (int n = 0; n < 4; ++n) RDB(bf[n], n, 0, cur);
#pragma unroll
    for (int m = 0; m < 4; ++m) RDA(af[m], m, 0, cur);
    MFMA_CLUSTER(0, af, bf);
    // ---- phase 1: ks=0, m-half 1 ----
    if (pf) {
      STB(0, kt + 1);
      asm volatile("s_waitcnt vmcnt(6)" ::: "memory");
    }
    __builtin_amdgcn_s_barrier();
    __builtin_amdgcn_sched_barrier(0);
#pragma unroll
    for (int m = 0; m < 4; ++m) RDA(af[m], 4 + m, 0, cur);
    MFMA_CLUSTER(4, af, bf);
    // ---- phase 2: ks=1, m-half 0 ----
    if (pf) {
      STA(1, kt + 1);
      asm volatile("s_waitcnt vmcnt(6)" ::: "memory");
    } else {
      asm volatile("s_waitcnt vmcnt(0)" ::: "memory");
    }
    __builtin_amdgcn_s_barrier();
    __builtin_amdgcn_sched_barrier(0);
#pragma unroll
    for (int n = 0; n < 4; ++n) RDB(bf[n], n, 1, cur);
#pragma unroll
    for (int m = 0; m < 4; ++m) RDA(af[m], m, 1, cur);
    MFMA_CLUSTER(0, af, bf);
    // ---- phase 3: ks=1, m-half 1 ----
    if (pf) {
      STB(1, kt + 1);
      asm volatile("s_waitcnt vmcnt(6)" ::: "memory");
    }
    __builtin_amdgcn_s_barrier();
    __builtin_amdgcn_sched_barrier(0);
#pragma unroll
    for (int m = 0; m < 4; ++m) RDA(af[m], 4 + m, 1, cur);
    MFMA_CLUSTER(4, af, bf);
  }
#undef STA
#undef STB
#undef RDA
#undef RDB
#undef MFMA_CLUSTER

  // ---------------- epilogue ----------------
#pragma unroll
  for (int m = 0; m < 8; ++m) {
#pragma unroll
    for (int n = 0; n < 4; ++n) {
#pragma unroll
      for (int jr = 0; jr < 4; ++jr) {
        const int rg = row0 + wm * 128 + m * 16 + kg * 4 + jr;
        const int cg = col0 + wn * 64 + n * 16 + rl;
        const float v = acc[m][n][jr] + bias[cg];
        if (EPI == 0) {
          ((float*)Cout)[(size_t)rg * N + cg] = v;
        } else {
          const float p = __shfl_xor(v, 1);
          const size_t cb = (size_t)rg * DHv + (cg & 63);
          const float cc = cs[cb], ss = sn[cb];
          // forward rotary: even d: v*c - p*s ; odd d: v*c + p*s
          const float y = (l & 1) ? (v * cc + p * ss) : (v * cc - p * ss);
          ((f16*)Cout)[(size_t)rg * N + cg] = (f16)y;
        }
      }
    }
  }
}

// ------- f16 MFMA GEMM, 128x128 tile, BK=32, counted-vmcnt pipeline -------
// (output projection; grid 256 blocks)
template <int EPI>
__global__ __launch_bounds__(256) void gemm_mfma(
    const f16* __restrict__ A, const f16* __restrict__ Bt,
    const float* __restrict__ bias, void* __restrict__ Cout,
    const float* __restrict__ cs, const float* __restrict__ sn,
    int M, int N, int K) {
  __shared__ __align__(16) f16 Asb[2][128 * 32];
  __shared__ __align__(16) f16 Bsb[2][128 * 32];
  const int t = threadIdx.x;
  const int l = t & 63, w = t >> 6;
  const int wr = w >> 1, wc = w & 1;
  const int row0 = blockIdx.y * 128, col0 = blockIdx.x * 128;

  const int i1 = t, i2 = t + 256;
  const f16* ga1 = &A[(size_t)(row0 + (i1 >> 2)) * K + (i1 & 3) * 8];
  const f16* ga2 = &A[(size_t)(row0 + (i2 >> 2)) * K + (i2 & 3) * 8];
  const f16* gb1 = &Bt[(size_t)(col0 + (i1 >> 2)) * K + (i1 & 3) * 8];
  const f16* gb2 = &Bt[(size_t)(col0 + (i2 >> 2)) * K + (i2 & 3) * 8];
  const int a_off1 = w * 512, a_off2 = w * 512 + 2048;

  const int rl = l & 15, kg = l >> 4;
  const int ar = (wr * 64 + rl) * 32 + kg * 8;
  const int br = (wc * 64 + rl) * 32 + kg * 8;

  const f32x4 zero = {0.f, 0.f, 0.f, 0.f};
  f32x4 acc[4][4];
#pragma unroll
  for (int m = 0; m < 4; ++m)
#pragma unroll
    for (int n = 0; n < 4; ++n) acc[m][n] = zero;

#define GSTAGE(buf, kk)                           \
  {                                               \
    gload16(ga1 + (kk)*32, &Asb[buf][a_off1]);    \
    gload16(ga2 + (kk)*32, &Asb[buf][a_off2]);    \
    gload16(gb1 + (kk)*32, &Bsb[buf][a_off1]);    \
    gload16(gb2 + (kk)*32, &Bsb[buf][a_off2]);    \
  }

  const int nt = K >> 5;
  GSTAGE(0, 0);

  for (int kt = 0; kt < nt; ++kt) {
    const int cur = kt & 1;
    if (kt + 1 < nt) {
      GSTAGE(cur ^ 1, kt + 1);
      asm volatile("s_waitcnt vmcnt(4)" ::: "memory");
    } else {
      asm volatile("s_waitcnt vmcnt(0)" ::: "memory");
    }
    __builtin_amdgcn_s_barrier();
    __builtin_amdgcn_sched_barrier(0);
    f16x8 af[4], bf[4];
#pragma unroll
    for (int m = 0; m < 4; ++m)
      af[m] = *reinterpret_cast<const f16x8*>(&Asb[cur][ar + m * 16 * 32]);
#pragma unroll
    for (int n = 0; n < 4; ++n)
      bf[n] = *reinterpret_cast<const f16x8*>(&Bsb[cur][br + n * 16 * 32]);
#pragma unroll
    for (int m = 0; m < 4; ++m)
#pragma unroll
      for (int n = 0; n < 4; ++n)
        acc[m][n] =
            __builtin_amdgcn_mfma_f32_16x16x32_f16(af[m], bf[n], acc[m][n], 0, 0, 0);
    asm volatile("" ::: "memory");
    __builtin_amdgcn_s_barrier();
    __builtin_amdgcn_sched_barrier(0);
  }
#undef GSTAGE

#pragma unroll
  for (int m = 0; m < 4; ++m) {
#pragma unroll
    for (int n = 0; n < 4; ++n) {
#pragma unroll
      for (int jr = 0; jr < 4; ++jr) {
        const int rg = row0 + wr * 64 + m * 16 + kg * 4 + jr;
        const int cg = col0 + wc * 64 + n * 16 + rl;
        const float v = acc[m][n][jr] + bias[cg];
        if (EPI == 0) {
          ((float*)Cout)[(size_t)rg * N + cg] = v;
        } else {
          const float p = __shfl_xor(v, 1);
          const size_t cb = (size_t)rg * DHv + (cg & 63);
          const float cc = cs[cb], ss = sn[cb];
          const float y = (l & 1) ? (v * cc + p * ss) : (v * cc - p * ss);
          ((f16*)Cout)[(size_t)rg * N + cg] = (f16)y;
        }
      }
    }
  }
}

// ---- V transpose: qkvf V-slab [n][d] -> vT[(b,h,d)][n'] with key perm ----
__global__ __launch_bounds__(256) void transpose_v(
    const f16* __restrict__ qkvf, f16* __restrict__ vT) {
  const int nt = blockIdx.x, hh = blockIdx.y, b = blockIdx.z;
  const int t = threadIdx.x;
  __shared__ __align__(16) f16 tile[64][80];  // [n-local][d]
  const int nl = t >> 3, dc = (t & 7) * 8;
#pragma unroll
  for (int half = 0; half < 2; ++half) {
    const int n = nl + half * 32;
    *reinterpret_cast<f16x8*>(&tile[n][dc]) = *reinterpret_cast<const f16x8*>(
        &qkvf[(size_t)(b * Nv + nt * 64 + n) * QKV3v + 2 * INNERv + hh * DHv + dc]);
  }
  __syncthreads();
  const int c0 = (t & 7) * 8;
  const int kwp = c0 >> 5, kgp = (c0 >> 3) & 3;
#pragma unroll
  for (int half = 0; half < 2; ++half) {
    const int d = (t >> 3) + half * 32;
    union { f16 e[8]; f16x8 v; } uo;
#pragma unroll
    for (int j = 0; j < 8; ++j) {
      const int mk = (j >> 2) & 1, jr = j & 3;
      const int kap = kwp * 32 + mk * 16 + kgp * 4 + jr;
      uo.e[j] = tile[kap][d];
    }
    *reinterpret_cast<f16x8*>(
        &vT[((size_t)((b * Hv + hh) * DHv + d)) * Nv + nt * 64 + c0]) = uo.v;
  }
}

// --------- MFMA flash attention v5: swapped QK^T, register P, O^T ---------
__global__ __launch_bounds__(256, 4) void attn_mfma(
    const f16* __restrict__ qkvf, const f16* __restrict__ vT,
    const float* __restrict__ cs, const float* __restrict__ sn,
    f16* __restrict__ ao) {
  const int wg = blockIdx.x;
  const int swz = (wg & 7) * 128 + (wg >> 3);
  const int qb = swz & 31;
  const int hh = (swz >> 5) & 15;
  const int b = swz >> 9;
  const int t = threadIdx.x, l = t & 63, w = t >> 6;
  const int qw = w >> 1, kw = w & 1;
  const int rl = l & 15, kg = l >> 4;

  __shared__ __align__(16) f16 KsB[2][64 * 64];
  __shared__ __align__(16) f16 VtB[2][64 * 64];
  __shared__ float Lbuf[2][2][32];

  const size_t qrow0 = (size_t)(b * Nv + qb * 64 + qw * 32);
  f16x8 bq[2][2];
#pragma unroll
  for (int nq = 0; nq < 2; ++nq)
#pragma unroll
    for (int ks = 0; ks < 2; ++ks)
      bq[nq][ks] = *reinterpret_cast<const f16x8*>(
          &qkvf[(qrow0 + nq * 16 + rl) * QKV3v + hh * DHv + ks * 32 + kg * 8]);

  const f32x4 zero = {0.f, 0.f, 0.f, 0.f};
  f32x4 o_acc[2][4];
  float l_part[2] = {0.f, 0.f};
#pragma unroll
  for (int nq = 0; nq < 2; ++nq)
#pragma unroll
    for (int m2 = 0; m2 < 4; ++m2) o_acc[nq][m2] = zero;

  const int srow = t >> 3, sc0 = (t & 7) * 8;
  const f16* vtbh = vT + (size_t)((b * Hv + hh) * DHv) * Nv;
  f16x8 kr0, kr1, vr0, vr1;

#define LOADKV(tile)                                                           \
  {                                                                            \
    const size_t kb0 =                                                         \
        (size_t)(b * Nv + (tile)*64 + srow) * QKV3v + INNERv + hh * DHv + sc0; \
    kr0 = *reinterpret_cast<const f16x8*>(&qkvf[kb0]);                         \
    kr1 = *reinterpret_cast<const f16x8*>(&qkvf[kb0 + (size_t)32 * QKV3v]);    \
    const size_t vb0 = (size_t)srow * Nv + (tile)*64 + sc0;                    \
    vr0 = *reinterpret_cast<const f16x8*>(&vtbh[vb0]);                         \
    vr1 = *reinterpret_cast<const f16x8*>(&vtbh[vb0 + (size_t)32 * Nv]);       \
  }
#define STOREKV(buf)                                                           \
  {                                                                            \
    const int r1 = srow + 32;                                                  \
    *reinterpret_cast<f16x8*>(                                                 \
        &KsB[buf][(srow << 6) | (sc0 ^ ((srow & 7) << 3))]) = kr0;             \
    *reinterpret_cast<f16x8*>(                                                 \
        &KsB[buf][(r1 << 6) | (sc0 ^ ((r1 & 7) << 3))]) = kr1;                 \
    *reinterpret_cast<f16x8*>(                                                 \
        &VtB[buf][(srow << 6) | (sc0 ^ ((srow & 7) << 3))]) = vr0;             \
    *reinterpret_cast<f16x8*>(                                                 \
        &VtB[buf][(r1 << 6) | (sc0 ^ ((r1 & 7) << 3))]) = vr1;                 \
  }

  LOADKV(0);
  STOREKV(0);
  LOADKV(1);
  __syncthreads();

  const float SC2 = 0.125f * 1.44269504f;

  for (int kt = 0; kt < 32; ++kt) {
    const int cur = kt & 1;
    const f16* Kc = &KsB[cur][0];
    const f16* Vc = &VtB[cur][0];

    f16x8 ak[2][2];
#pragma unroll
    for (int mk = 0; mk < 2; ++mk)
#pragma unroll
      for (int ks = 0; ks < 2; ++ks)
        ak[mk][ks] = *reinterpret_cast<const f16x8*>(
            &Kc[((kw * 32 + mk * 16 + rl) << 6) |
                ((ks * 32 + kg * 8) ^ ((rl & 7) << 3))]);
    f16x8 av[4];
#pragma unroll
    for (int m2 = 0; m2 < 4; ++m2)
      av[m2] = *reinterpret_cast<const f16x8*>(
          &Vc[((m2 * 16 + rl) << 6) |
              ((kw * 32 + kg * 8) ^ ((rl & 7) << 3))]);

    f32x4 sa[2][2];
#pragma unroll
    for (int mk = 0; mk < 2; ++mk)
#pragma unroll
      for (int nq = 0; nq < 2; ++nq) sa[mk][nq] = zero;
    __builtin_amdgcn_s_setprio(1);
#pragma unroll
    for (int ks = 0; ks < 2; ++ks)
#pragma unroll
      for (int mk = 0; mk < 2; ++mk)
#pragma unroll
        for (int nq = 0; nq < 2; ++nq)
          sa[mk][nq] = __builtin_amdgcn_mfma_f32_16x16x32_f16(
              ak[mk][ks], bq[nq][ks], sa[mk][nq], 0, 0, 0);
    __builtin_amdgcn_s_setprio(0);

    f16x8 pb[2];
#pragma unroll
    for (int nq = 0; nq < 2; ++nq) {
      float p00 = exp2f(fminf(sa[0][nq][0] * SC2, 13.0f));
      float p01 = exp2f(fminf(sa[0][nq][1] * SC2, 13.0f));
      float p02 = exp2f(fminf(sa[0][nq][2] * SC2, 13.0f));
      float p03 = exp2f(fminf(sa[0][nq][3] * SC2, 13.0f));
      float p10 = exp2f(fminf(sa[1][nq][0] * SC2, 13.0f));
      float p11 = exp2f(fminf(sa[1][nq][1] * SC2, 13.0f));
      float p12 = exp2f(fminf(sa[1][nq][2] * SC2, 13.0f));
      float p13 = exp2f(fminf(sa[1][nq][3] * SC2, 13.0f));
      l_part[nq] += ((p00 + p01) + (p02 + p03)) + ((p10 + p11) + (p12 + p13));
      union { hf2 h2[4]; f16x8 v; } u;
      u.h2[0] = __builtin_amdgcn_cvt_pkrtz(p00, p01);
      u.h2[1] = __builtin_amdgcn_cvt_pkrtz(p02, p03);
      u.h2[2] = __builtin_amdgcn_cvt_pkrtz(p10, p11);
      u.h2[3] = __builtin_amdgcn_cvt_pkrtz(p12, p13);
      pb[nq] = u.v;
    }

    __builtin_amdgcn_s_setprio(1);
#pragma unroll
    for (int nq = 0; nq < 2; ++nq)
#pragma unroll
      for (int m2 = 0; m2 < 4; ++m2)
        o_acc[nq][m2] = __builtin_amdgcn_mfma_f32_16x16x32_f16(
            av[m2], pb[nq], o_acc[nq][m2], 0, 0, 0);
    __builtin_amdgcn_s_setprio(0);

    if (kt < 31) STOREKV(1 - cur);
    if (kt < 30) LOADKV(kt + 2);
    __syncthreads();
  }

#pragma unroll
  for (int nq = 0; nq < 2; ++nq) {
    l_part[nq] += __shfl_xor(l_part[nq], 16);
    l_part[nq] += __shfl_xor(l_part[nq], 32);
  }
  if (kg == 0) {
    Lbuf[qw][kw][rl] = l_part[0];
    Lbuf[qw][kw][16 + rl] = l_part[1];
  }
  {
    char* ob = (qw == 0 ? (char*)KsB : (char*)VtB) + kw * 8192;
#pragma unroll
    for (int nq = 0; nq < 2; ++nq)
#pragma unroll
      for (int m2 = 0; m2 < 4; ++m2)
        *reinterpret_cast<f32x4*>(
            ob + (nq * 16 + rl) * 256 +
            ((m2 * 64 + kg * 16) ^ ((rl & 7) << 4))) = o_acc[nq][m2];
  }
  __syncthreads();
  {
    const int q_local = w * 16 + (l >> 2);
    const int qw_r = q_local >> 5, q_in = q_local & 31;
    const int d0 = (l & 3) * 16;
    char* rb = (qw_r == 0 ? (char*)KsB : (char*)VtB);
    const float linv = 1.0f / (Lbuf[qw_r][0][q_in] + Lbuf[qw_r][1][q_in]);
    const size_t nq_g = (size_t)(b * Nv + qb * 64 + q_local);
    const size_t cb = nq_g * DHv + d0;
    union { f16 e[16]; f16x8 v[2]; } uo;
#pragma unroll
    for (int j = 0; j < 4; ++j) {
      const unsigned off = q_in * 256 + (((l & 3) * 64 + j * 16) ^ ((q_in & 7) << 4));
      const f32x4 a = *reinterpret_cast<const f32x4*>(rb + off);
      const f32x4 c2 = *reinterpret_cast<const f32x4*>(rb + 8192 + off);
      const float4 csv = *reinterpret_cast<const float4*>(&cs[cb + j * 4]);
      const float4 snv = *reinterpret_cast<const float4*>(&sn[cb + j * 4]);
      const float o0 = (a[0] + c2[0]) * linv;
      const float o1 = (a[1] + c2[1]) * linv;
      const float o2 = (a[2] + c2[2]) * linv;
      const float o3 = (a[3] + c2[3]) * linv;
      uo.e[j * 4 + 0] = (f16)(o0 * csv.x + o1 * snv.x);
      uo.e[j * 4 + 1] = (f16)(o1 * csv.y - o0 * snv.y);
      uo.e[j * 4 + 2] = (f16)(o2 * csv.z + o3 * snv.z);
      uo.e[j * 4 + 3] = (f16)(o3 * csv.w - o2 * snv.w);
    }
    f16* aop = &ao[nq_g * INNERv + hh * DHv + d0];
    *reinterpret_cast<f16x8*>(aop) = uo.v[0];
    *reinterpret_cast<f16x8*>(aop + 8) = uo.v[1];
  }
#undef LOADKV
#undef STOREKV
}

extern "C" void kernel_launch(void* const* d_in, const int* in_sizes, int n_in,
                              void* d_out, int out_size, void* d_ws, size_t ws_size,
                              hipStream_t stream) {
  (void)in_sizes; (void)n_in; (void)out_size; (void)ws_size;
  const float* x = (const float*)d_in[0];
  const float* rot = (const float*)d_in[1];
  const float* ln_g = (const float*)d_in[2];
  const float* ln_b = (const float*)d_in[3];
  const float* w_qkv = (const float*)d_in[4];
  const float* b_qkv = (const float*)d_in[5];
  const float* w_out = (const float*)d_in[6];
  const float* b_out = (const float*)d_in[7];

  char* p = (char*)d_ws;
  f16* h = (f16*)p;            p += (size_t)Bv * Nv * DIMv * 2;
  float* cs = (float*)p;       p += (size_t)Bv * Nv * DHv * 4;
  float* sn = (float*)p;       p += (size_t)Bv * Nv * DHv * 4;
  f16* wqT = (f16*)p;          p += (size_t)QKV3v * DIMv * 2;
  f16* woT = (f16*)p;          p += (size_t)DIMv * INNERv * 2;
  f16* qkvf = (f16*)p;         p += (size_t)Bv * Nv * QKV3v * 2;
  f16* ao = (f16*)p;           p += (size_t)Bv * Nv * INNERv * 2;
  f16* vT = (f16*)p;           p += (size_t)Bv * Hv * DHv * Nv * 2;

  ln_kernel<<<dim3(Bv * Nv), dim3(256), 0, stream>>>(x, ln_g, ln_b, h);
  rotcs_kernel<<<dim3((Bv * Nv * DHv) / 256), dim3(256), 0, stream>>>(
      rot, cs, sn, Bv * Nv * DHv);
  transpose_f16<<<dim3(QKV3v / 64, DIMv / 64), dim3(256), 0, stream>>>(
      w_qkv, wqT, DIMv, QKV3v);
  transpose_f16<<<dim3(INNERv / 64, DIMv / 64), dim3(256), 0, stream>>>(
      w_out, woT, DIMv, INNERv);
  gemm_mfma256<1><<<dim3(QKV3v / 256, (Bv * Nv) / 256), dim3(512), 0, stream>>>(
      h, wqT, b_qkv, (void*)qkvf, cs, sn, Bv * Nv, QKV3v, DIMv);
  transpose_v<<<dim3(Nv / 64, Hv, Bv), dim3(256), 0, stream>>>(qkvf, vT);
  attn_mfma<<<dim3(1024), dim3(256), 0, stream>>>(qkvf, vT, cs, sn, ao);
  gemm_mfma<0><<<dim3(DIMv / 128, (Bv * Nv) / 128), dim3(256), 0, stream>>>(
      ao, woT, b_out, d_out, nullptr, nullptr, Bv * Nv, DIMv, INNERv);
}